// Round 9
// baseline (728.869 us; speedup 1.0000x reference)
//
#include <hip/hip_runtime.h>
#include <hip/hip_fp16.h>
#include <hip/hip_cooperative_groups.h>

namespace cg = cooperative_groups;

#define N_TRAIN   2048
#define DOUT      16
#define DACT      8
#define DIN       24
#define HORIZON   64
#define JITTER    1e-6f

#define NBLK      256
#define NTHR      1024
#define RPB       8        // rows per block: 2048/256
#define SQS       2056     // fp16 sq LDS stride (16B-aligned rows)

#define POWER_ITERS 5
#define RICH_NORM   7      // it=0..7 inclusive -> 8 G-applications (first fused)
#define MAXPC       14
#define FRAME       12288  // 48 slots * 16 lanes * 16-float spacing

// workspace layout (float indices): 14 round-robin V buffers (write-once via
// MALL astore, read-once-per-address via cached float4 -> no staleness), then
// YB, RES partial frames, sync lines.
#define OFF_V     0                          // V[i] = ws + i*32768, i=0..13
#define OFF_YB    (14*32768)
#define OFF_RES   (OFF_YB + 32768)
#define OFF_SYN   (OFF_RES + MAXPC*FRAME)    // u32: 16 arrival + 16 gen lines

__device__ __forceinline__ float fexp2(float x){ return __builtin_amdgcn_exp2f(x); }

// MALL-direct (agent-scope, relaxed) accessors for cross-block WRITES and
// RES readbacks. No fences anywhere after init; L2 never invalidated.
__device__ __forceinline__ float aload(const float* p){
  unsigned int v = __hip_atomic_load((const unsigned int*)p, __ATOMIC_RELAXED,
                                     __HIP_MEMORY_SCOPE_AGENT);
  union { unsigned int u; float f; } c; c.u = v; return c.f;
}
__device__ __forceinline__ void astore(float* p, float v){
  union { float f; unsigned int u; } c; c.f = v;
  __hip_atomic_store((unsigned int*)p, c.u, __ATOMIC_RELAXED, __HIP_MEMORY_SCOPE_AGENT);
}

// Two-level fence-free grid barrier. 16 arrival lines (release RMW), block 0
// detects, publishes pc to 16 gen lines; followers poll their own line.
__device__ __forceinline__ void gbar_pre(unsigned int* syn, int pc, bool spin){
  __syncthreads();
  if (threadIdx.x == 0){
    __hip_atomic_fetch_add(&syn[(blockIdx.x & 15) * 16], 1u,
                           __ATOMIC_RELEASE, __HIP_MEMORY_SCOPE_AGENT);
  }
  if (!spin) return;
  if (blockIdx.x == 0){
    if (threadIdx.x < 64){
      const unsigned int target = (unsigned int)pc * NBLK;
      while (true){
        unsigned int v = (threadIdx.x < 16)
          ? __hip_atomic_load(&syn[threadIdx.x * 16], __ATOMIC_RELAXED,
                              __HIP_MEMORY_SCOPE_AGENT) : 0u;
        v += __shfl_xor(v, 1); v += __shfl_xor(v, 2);
        v += __shfl_xor(v, 4); v += __shfl_xor(v, 8);
        if (__shfl(v, 0) >= target) break;
        __builtin_amdgcn_s_sleep(1);
      }
      if (threadIdx.x < 16)
        __hip_atomic_store(&syn[256 + threadIdx.x * 16], (unsigned int)pc,
                           __ATOMIC_RELAXED, __HIP_MEMORY_SCOPE_AGENT);
    }
  } else if (threadIdx.x == 0){
    unsigned int* g = &syn[256 + (blockIdx.x & 15) * 16];
    while (__hip_atomic_load(g, __ATOMIC_RELAXED, __HIP_MEMORY_SCOPE_AGENT)
           < (unsigned int)pc){
      __builtin_amdgcn_s_sleep(2);
    }
  }
  __syncthreads();
}

// w = G_d * u over this block's 8 rows; sq from LDS fp16; u via cached float4
// (hoisted upfront). MODE 0: u = V. MODE 2 (fused a0): u = YB - cbsig*V.
template<int MODE>
__device__ __forceinline__ void sweep(const __half* sqh, const float* __restrict__ V,
                                      const float* __restrict__ YB, float cbsig,
                                      float ce, float gd, float* wfin,
                                      int rowbase, int d, int jg)
{
  float u[32];
#pragma unroll
  for (int seg = 0; seg < 4; ++seg){
    const int j0 = 8 * jg + 512 * seg;
    float4 ua = *reinterpret_cast<const float4*>(&V[d * N_TRAIN + j0]);
    float4 ub = *reinterpret_cast<const float4*>(&V[d * N_TRAIN + j0 + 4]);
    if (MODE == 2){
      float4 ya = *reinterpret_cast<const float4*>(&YB[d * N_TRAIN + j0]);
      float4 yb = *reinterpret_cast<const float4*>(&YB[d * N_TRAIN + j0 + 4]);
      ua.x = ya.x - cbsig * ua.x;  ua.y = ya.y - cbsig * ua.y;
      ua.z = ya.z - cbsig * ua.z;  ua.w = ya.w - cbsig * ua.w;
      ub.x = yb.x - cbsig * ub.x;  ub.y = yb.y - cbsig * ub.y;
      ub.z = yb.z - cbsig * ub.z;  ub.w = yb.w - cbsig * ub.w;
    }
    u[seg*8+0]=ua.x; u[seg*8+1]=ua.y; u[seg*8+2]=ua.z; u[seg*8+3]=ua.w;
    u[seg*8+4]=ub.x; u[seg*8+5]=ub.y; u[seg*8+6]=ub.z; u[seg*8+7]=ub.w;
  }
  float acc[RPB];
#pragma unroll
  for (int r = 0; r < RPB; ++r) acc[r] = 0.f;
#pragma unroll
  for (int seg = 0; seg < 4; ++seg){
    const int j0 = 8 * jg + 512 * seg;
#pragma unroll
    for (int r = 0; r < RPB; ++r){
      uint4 sp = *reinterpret_cast<const uint4*>(&sqh[r * SQS + j0]);
      unsigned int w4[4] = {sp.x, sp.y, sp.z, sp.w};
#pragma unroll
      for (int e = 0; e < 4; ++e){
        __half2 h2 = *reinterpret_cast<const __half2*>(&w4[e]);
        float2 f2 = __half22float2(h2);
        acc[r] = fmaf(fexp2(ce * f2.x), u[seg*8 + 2*e],     acc[r]);
        acc[r] = fmaf(fexp2(ce * f2.y), u[seg*8 + 2*e + 1], acc[r]);
      }
    }
  }
#pragma unroll
  for (int r = 0; r < RPB; ++r){
    acc[r] += __shfl_xor(acc[r], 1);
    acc[r] += __shfl_xor(acc[r], 2);
    acc[r] += __shfl_xor(acc[r], 4);
    acc[r] += __shfl_xor(acc[r], 8);
    acc[r] += __shfl_xor(acc[r], 16);
    acc[r] += __shfl_xor(acc[r], 32);
  }
  if (jg == 0){
#pragma unroll
    for (int r = 0; r < RPB; ++r){
      const int rowg = rowbase + r;
      float ud = V[d * N_TRAIN + rowg];
      if (MODE == 2) ud = YB[d * N_TRAIN + rowg] - cbsig * ud;
      wfin[r * 16 + d] = gd * (acc[r] - ud);   // subtract diagonal (sq=0 -> exp=1)
    }
  }
}

__global__ __launch_bounds__(NTHR, 1)
void gp_rollout_kernel(const float* __restrict__ xtr, const float* __restrict__ ytr,
                       const float* __restrict__ ls,  const float* __restrict__ var,
                       const float* __restrict__ noi, const float* __restrict__ st0,
                       const float* __restrict__ act, const float* __restrict__ eps,
                       float* __restrict__ out, float* __restrict__ ws)
{
  cg::grid_group grid = cg::this_grid();
  const int tid = threadIdx.x;
  const int bid = blockIdx.x;
  const int rowbase = bid * RPB;

  float* YB  = ws + OFF_YB;
  float* RES = ws + OFF_RES;
  unsigned int* syn = (unsigned int*)(ws + OFF_SYN);
#define VBUF(i) (ws + OFF_V + (i) * 32768)

  __shared__ __half sqh[RPB * SQS];            // 32.9 KB
  __shared__ float act_s[HORIZON * DACT];      // 2 KB
  __shared__ float eps_s[HORIZON * DOUT];      // 4 KB
  __shared__ float d2f[N_TRAIN];               // 8 KB (rollout only)
  __shared__ float pr[384];
  __shared__ float wfin[128];
  __shared__ float dsum[48];
  __shared__ float xcur[32];
  __shared__ float xrows[RPB * DIN];
  __shared__ float pv_s[128], v_s[128], yb_s[128];
  __shared__ float ce_s[16], g_s[16], s_s[16], var_s[16], nv_s[16];
  __shared__ float un_s[16], lam_s[16], sig_s[16], cb_s[16], ca_s[16];

  if (tid < 16){
    float l2 = ls[tid] * ls[tid];
    float nv = noi[tid] * noi[tid];
    float sd = var[tid] + nv + JITTER;
    ce_s[tid]  = -0.72134752044448f / l2;   // -0.5*log2(e)/ls^2
    g_s[tid]   = var[tid] / sd;
    s_s[tid]   = sd;
    var_s[tid] = var[tid];
    nv_s[tid]  = nv;
    un_s[tid]  = (float)N_TRAIN;            // ||ones||^2
  }
  if (tid < RPB * DIN) xrows[tid] = xtr[rowbase * DIN + tid];
  if (tid < HORIZON * DACT) act_s[tid] = act[tid];
  if (tid < HORIZON * DOUT) eps_s[tid] = eps[tid];
  __syncthreads();

  // -------- Phase 0: sq rows -> LDS fp16; YB/V0 seed; zero RES+syn ----------
  if (tid < 128){
    const int dd = tid >> 3, r = tid & 7;
    float yb = ytr[(rowbase + r) * DOUT + dd] / s_s[dd];
    yb_s[tid] = yb;
    astore(&YB[dd * N_TRAIN + rowbase + r], yb);
    astore(&VBUF(0)[dd * N_TRAIN + rowbase + r], 1.0f);
    pv_s[tid] = 1.0f;
  }
  {
    const int r  = tid >> 7;      // 0..7, 128 threads per row
    const int c0 = tid & 127;
    float xl[DIN];
#pragma unroll
    for (int k = 0; k < DIN; ++k) xl[k] = xrows[r * DIN + k];
    for (int q = 0; q < 16; ++q){
      const int j = c0 + (q << 7);
      const float4* xp = reinterpret_cast<const float4*>(xtr + j * DIN);
      float sacc = 0.f;
#pragma unroll
      for (int v4 = 0; v4 < 6; ++v4){
        float4 x4 = xp[v4];
        float e0 = xl[v4*4+0] - x4.x, e1 = xl[v4*4+1] - x4.y;
        float e2 = xl[v4*4+2] - x4.z, e3 = xl[v4*4+3] - x4.w;
        sacc = fmaf(e0,e0, fmaf(e1,e1, fmaf(e2,e2, fmaf(e3,e3, sacc))));
      }
      sqh[r * SQS + j] = __float2half_rn(sacc);
    }
  }
  {
    int i = bid * NTHR + tid;
    if (i < MAXPC * FRAME) RES[i] = 0.f;       // regular stores; grid.sync flushes
  }
  if (bid == 0 && tid < 512) syn[tid] = 0u;
  __syncthreads();
  __threadfence();
  grid.sync();            // single cooperative sync: init visibility everywhere
  int pc = 0;

  const int d  = tid >> 6;   // 0..15, one wave per output
  const int jg = tid & 63;
  const int lane16 = bid & 15;

  // -------- Power iteration (5): read VBUF(it), write VBUF(it+1) -------------
#pragma unroll 1
  for (int it = 0; it < POWER_ITERS; ++it){
    const bool last = (it == POWER_ITERS - 1);
    float* PVc = VBUF(it);
    float* PVn = VBUF(it + 1);
    sweep<0>(sqh, PVc, YB, 0.f, ce_s[d], g_s[d], wfin, rowbase, d, jg);
    __syncthreads();
    if (tid < 128){
      const int dd = tid >> 3, r = tid & 7, rowg = rowbase + r;
      float w = wfin[r * 16 + dd];
      astore(&PVn[dd * N_TRAIN + rowg], w);
      float u = pv_s[tid];
      pv_s[tid] = w;
      pr[tid]       = w * w;
      pr[128 + tid] = u * w;
      pr[256 + tid] = last ? yb_s[tid] * w : 0.f;
    }
    __syncthreads();
    ++pc;
    if (tid < 48){
      const int slot = tid >> 4, dd = tid & 15;
      float s = 0.f;
#pragma unroll
      for (int r = 0; r < 8; ++r) s += pr[slot * 128 + dd * 8 + r];
      atomicAdd(&RES[pc * FRAME + (tid * 16 + lane16) * 16], s);
    }
    gbar_pre(syn, pc, true);
    if (tid < 48){
      const float* base = &RES[pc * FRAME + tid * 256];
      float s = 0.f;
#pragma unroll
      for (int l = 0; l < 16; ++l) s += aload(base + l * 16);
      dsum[tid] = s;
    }
    __syncthreads();
    if (tid < 16){
      float ww = dsum[tid];        // slot0: w.w
      float uw = dsum[16 + tid];   // slot1: u.w
      if (last){
        lam_s[tid] = uw / fmaxf(un_s[tid], 1e-30f);   // Rayleigh quotient
        float sg = rsqrtf(fmaxf(ww, 1e-38f));
        sig_s[tid] = sg;
        cb_s[tid]  = sg * dsum[32 + tid];              // v1^T (y/s)
      }
      un_s[tid] = ww;
    }
    __syncthreads();
  }

  if (tid < 128){
    const int dd = tid >> 3;
    v_s[tid] = sig_s[dd] * pv_s[tid];
  }
  if (tid < 16) ca_s[tid] = 0.f;     // v unit => v^T a0 = cb - cb = 0
  __syncthreads();

  // -------- Richardson (8 apps, first fused): a_{k+1} = b_perp - Gt a_k ------
#pragma unroll 1
  for (int it = 0; it <= RICH_NORM; ++it){
    const bool last = (it == RICH_NORM);
    float* Aout = VBUF(6 + it);                       // it=7 -> VBUF(13) = ALPH
    if (it == 0)
      sweep<2>(sqh, VBUF(POWER_ITERS), YB, cb_s[d] * sig_s[d],
               ce_s[d], g_s[d], wfin, rowbase, d, jg);
    else
      sweep<0>(sqh, VBUF(6 + it - 1), YB, 0.f,
               ce_s[d], g_s[d], wfin, rowbase, d, jg);
    __syncthreads();
    if (tid < 128){
      const int dd = tid >> 3, r = tid & 7, rowg = rowbase + r;
      float w = wfin[r * 16 + dd];
      float v = v_s[tid];
      float bperp = yb_s[tid] - cb_s[dd] * v;
      float anew = bperp - (w - lam_s[dd] * ca_s[dd] * v);
      if (last){
        astore(&Aout[dd * N_TRAIN + rowg], anew + (cb_s[dd] / (1.f + lam_s[dd])) * v);
      } else {
        astore(&Aout[dd * N_TRAIN + rowg], anew);
        pr[tid] = v * anew;
      }
    }
    __syncthreads();
    ++pc;
    if (last){
      gbar_pre(syn, pc, bid == 0);   // blocks != 0: arrive-only, exit
      if (bid != 0) return;
      break;
    }
    if (tid < 16){
      float s = 0.f;
#pragma unroll
      for (int r = 0; r < 8; ++r) s += pr[tid * 8 + r];
      atomicAdd(&RES[pc * FRAME + (tid * 16 + lane16) * 16], s);
    }
    gbar_pre(syn, pc, true);
    if (tid < 16){
      const float* base = &RES[pc * FRAME + tid * 256];
      float s = 0.f;
#pragma unroll
      for (int l = 0; l < 16; ++l) s += aload(base + l * 16);
      ca_s[tid] = s;
    }
    __syncthreads();
  }

  // ======== Rollout: block 0 only, zero cross-block traffic ==================
  // Wave w owns output w. alpha/v in registers (lane l owns points l+64q).
  const int w  = tid >> 6;
  const int l  = tid & 63;
  const float ced = ce_s[w], vd = var_s[w], sg = sig_s[w];
  const float* AL = VBUF(6 + RICH_NORM);     // cold lines -> fresh from MALL
  const float* PV = VBUF(POWER_ITERS);       // cached from rich it0 (never rewritten)
  float ar[32], vr[32];
#pragma unroll
  for (int q = 0; q < 32; ++q){
    const int j = l + 64 * q;
    ar[q] = AL[w * N_TRAIN + j];
    vr[q] = sg * PV[w * N_TRAIN + j];
  }
  if (tid < 16) xcur[tid] = st0[tid];
  if (tid >= 16 && tid < 24) xcur[tid] = act_s[tid - 16];
  __syncthreads();

#pragma unroll 1
  for (int t = 0; t < HORIZON; ++t){
    // d2 for points 2tid, 2tid+1 (xtr L2-hot, fp32-exact)
    {
      const float4* pa = reinterpret_cast<const float4*>(xtr + 2 * tid * DIN);
      float sx = 0.f, sy = 0.f;
#pragma unroll
      for (int v4 = 0; v4 < 6; ++v4){
        float4 a4 = pa[v4];          // point 2tid coords 4v4..4v4+3
        float4 b4 = pa[6 + v4];      // point 2tid+1
        float c0 = xcur[4*v4+0], c1 = xcur[4*v4+1];
        float c2 = xcur[4*v4+2], c3 = xcur[4*v4+3];
        float e;
        e = c0 - a4.x; sx = fmaf(e, e, sx);   e = c0 - b4.x; sy = fmaf(e, e, sy);
        e = c1 - a4.y; sx = fmaf(e, e, sx);   e = c1 - b4.y; sy = fmaf(e, e, sy);
        e = c2 - a4.z; sx = fmaf(e, e, sx);   e = c2 - b4.z; sy = fmaf(e, e, sy);
        e = c3 - a4.w; sx = fmaf(e, e, sx);   e = c3 - b4.w; sy = fmaf(e, e, sy);
      }
      *reinterpret_cast<float2*>(&d2f[2 * tid]) = make_float2(sx, sy);
    }
    __syncthreads();
    // wave w: full dots for output w
    {
      float am = 0.f, ac = 0.f, ak = 0.f;
#pragma unroll
      for (int q = 0; q < 32; ++q){
        float k0 = vd * fexp2(ced * d2f[l + 64 * q]);
        am = fmaf(k0, ar[q], am);
        ac = fmaf(k0, vr[q], ac);
        ak = fmaf(k0, k0,  ak);
      }
#pragma unroll
      for (int off = 1; off < 64; off <<= 1){
        am += __shfl_xor(am, off);
        ac += __shfl_xor(ac, off);
        ak += __shfl_xor(ak, off);
      }
      if (l == 0){ pr[w*3+0] = am; pr[w*3+1] = ac; pr[w*3+2] = ak; }
    }
    __syncthreads();
    if (tid < 16){
      const int dd = tid;
      float mean = pr[3*dd], c = pr[3*dd+1], kk = pr[3*dd+2];
      float lam = lam_s[dd];
      float qs = c * c / (1.f + lam) + (kk - c * c);   // k^T Ky^-1 k * s
      float q  = qs / s_s[dd];
      float pvv = var_s[dd] - q + nv_s[dd];
      float sd = sqrtf(fmaxf(pvv, 1e-12f));
      float ns = mean + sd * eps_s[t * DOUT + dd];
      xcur[dd] = ns;
      float rs = ns, cs = ns * ns;
      rs += __shfl_down(rs, 8);  cs += __shfl_down(cs, 8);
      rs += __shfl_down(rs, 4);  cs += __shfl_down(cs, 4);
      rs += __shfl_down(rs, 2);  cs += __shfl_down(cs, 2);
      rs += __shfl_down(rs, 1);  cs += __shfl_down(cs, 1);
      out[t * DOUT + dd]        = ns;     // trajectory
      out[1152 + t * DOUT + dd] = mean;   // means
      out[2176 + t * DOUT + dd] = sd;     // stds
      if (dd == 0){ out[1024 + t] = rs; out[1088 + t] = cs; }  // reward, cost
    } else if (tid >= 16 && tid < 24 && t + 1 < HORIZON){
      xcur[tid] = act_s[(t + 1) * DACT + (tid - 16)];
    }
    __syncthreads();
  }
#undef VBUF
}

extern "C" void kernel_launch(void* const* d_in, const int* in_sizes, int n_in,
                              void* d_out, int out_size, void* d_ws, size_t ws_size,
                              hipStream_t stream) {
  (void)in_sizes; (void)n_in; (void)out_size; (void)ws_size;
  const float* xtr = (const float*)d_in[0];
  const float* ytr = (const float*)d_in[1];
  const float* ls  = (const float*)d_in[2];
  const float* var = (const float*)d_in[3];
  const float* noi = (const float*)d_in[4];
  const float* st0 = (const float*)d_in[5];
  const float* act = (const float*)d_in[6];
  const float* eps = (const float*)d_in[7];
  float* out = (float*)d_out;
  float* ws  = (float*)d_ws;
  void* args[] = { &xtr, &ytr, &ls, &var, &noi, &st0, &act, &eps, &out, &ws };
  hipLaunchCooperativeKernel((const void*)gp_rollout_kernel,
                             dim3(NBLK), dim3(NTHR), args, 0, stream);
}

// Round 10
// 668.612 us; speedup vs baseline: 1.0901x; 1.0901x over previous
//
#include <hip/hip_runtime.h>
#include <hip/hip_fp16.h>
#include <hip/hip_cooperative_groups.h>

namespace cg = cooperative_groups;

#define N_TRAIN   2048
#define DOUT      16
#define DACT      8
#define DIN       24
#define HORIZON   64
#define JITTER    1e-6f

#define NBLK      128
#define NTHR      1024
#define RPB       16       // rows per block: 2048/128
#define SQS       2056     // fp16 sq LDS stride (16B-aligned rows)
#define NROLL     16       // rollout blocks, one GP output each

#define POWER_ITERS 5
#define RICH_ITERS  8
#define MAXPC       16

// workspace layout (float indices) — r8 layout
#define OFF_PV0   0
#define OFF_PV1   32768
#define OFF_AA0   65536
#define OFF_AA1   98304
#define OFF_AL    131072
#define OFF_RES   163840                    // MAXPC frames * 6144 floats
#define OFF_SYN   (OFF_RES + MAXPC*6144)    // u32: 8 arrival + 8 gen lines
#define OFF_RES2  (OFF_SYN + 1024)          // 64 steps * 64 float2 (value,tag)

__device__ __forceinline__ float fexp2(float x){ return __builtin_amdgcn_exp2f(x); }

// MALL-direct (agent-scope, relaxed) accessors — no fences, L2 never invalidated.
__device__ __forceinline__ float aload(const float* p){
  unsigned int v = __hip_atomic_load((const unsigned int*)p, __ATOMIC_RELAXED,
                                     __HIP_MEMORY_SCOPE_AGENT);
  union { unsigned int u; float f; } c; c.u = v; return c.f;
}
__device__ __forceinline__ float2 aload2(const float* p){
  unsigned long long v = __hip_atomic_load((const unsigned long long*)p,
                                           __ATOMIC_RELAXED, __HIP_MEMORY_SCOPE_AGENT);
  union { unsigned long long u; float2 f; } c; c.u = v; return c.f;
}
__device__ __forceinline__ void astore(float* p, float v){
  union { float f; unsigned int u; } c; c.f = v;
  __hip_atomic_store((unsigned int*)p, c.u, __ATOMIC_RELAXED, __HIP_MEMORY_SCOPE_AGENT);
}
__device__ __forceinline__ void astore2(float* p, float2 v){
  union { float2 f; unsigned long long u; } c; c.f = v;
  __hip_atomic_store((unsigned long long*)p, c.u, __ATOMIC_RELAXED,
                     __HIP_MEMORY_SCOPE_AGENT);
}

// Two-level fence-free grid barrier (precompute only) — r8 verbatim.
__device__ __forceinline__ void gbar_pre(unsigned int* syn, int pc, bool spin){
  __syncthreads();
  if (threadIdx.x == 0){
    __hip_atomic_fetch_add(&syn[(blockIdx.x & 7) * 16], 1u,
                           __ATOMIC_RELEASE, __HIP_MEMORY_SCOPE_AGENT);
  }
  if (!spin) return;
  if (blockIdx.x == 0){
    if (threadIdx.x < 64){
      const unsigned int target = (unsigned int)pc * NBLK;
      while (true){
        unsigned int v = (threadIdx.x < 8)
          ? __hip_atomic_load(&syn[threadIdx.x * 16], __ATOMIC_RELAXED,
                              __HIP_MEMORY_SCOPE_AGENT) : 0u;
        v += __shfl_xor(v, 1); v += __shfl_xor(v, 2); v += __shfl_xor(v, 4);
        if (__shfl(v, 0) >= target) break;
        __builtin_amdgcn_s_sleep(1);
      }
      if (threadIdx.x < 8)
        __hip_atomic_store(&syn[128 + threadIdx.x * 16], (unsigned int)pc,
                           __ATOMIC_RELAXED, __HIP_MEMORY_SCOPE_AGENT);
    }
  } else if (threadIdx.x == 0){
    unsigned int* g = &syn[128 + (blockIdx.x & 7) * 16];
    while (__hip_atomic_load(g, __ATOMIC_RELAXED, __HIP_MEMORY_SCOPE_AGENT)
           < (unsigned int)pc){
      __builtin_amdgcn_s_sleep(2);
    }
  }
  __syncthreads();
}

// w = G_d * u over this block's 16 rows; sq from LDS fp16; u via MALL aload2
// (r8-proven path).
__device__ __forceinline__ void sweep(const __half* sqh, const float* __restrict__ V,
                                      float ce, float gd, float* wfin,
                                      int rowbase, int d, int jg)
{
  float acc[RPB];
#pragma unroll
  for (int r = 0; r < RPB; ++r) acc[r] = 0.f;
#pragma unroll
  for (int seg = 0; seg < 4; ++seg){
    const int j0 = 8 * jg + 512 * seg;
    float2 u01 = aload2(&V[d * N_TRAIN + j0]);
    float2 u23 = aload2(&V[d * N_TRAIN + j0 + 2]);
    float2 u45 = aload2(&V[d * N_TRAIN + j0 + 4]);
    float2 u67 = aload2(&V[d * N_TRAIN + j0 + 6]);
    float u[8] = {u01.x, u01.y, u23.x, u23.y, u45.x, u45.y, u67.x, u67.y};
#pragma unroll
    for (int r = 0; r < RPB; ++r){
      uint4 sp = *reinterpret_cast<const uint4*>(&sqh[r * SQS + j0]);
      unsigned int w4[4] = {sp.x, sp.y, sp.z, sp.w};
#pragma unroll
      for (int e = 0; e < 4; ++e){
        __half2 h2 = *reinterpret_cast<const __half2*>(&w4[e]);
        float2 f2 = __half22float2(h2);
        acc[r] = fmaf(fexp2(ce * f2.x), u[2*e],   acc[r]);
        acc[r] = fmaf(fexp2(ce * f2.y), u[2*e+1], acc[r]);
      }
    }
  }
#pragma unroll
  for (int r = 0; r < RPB; ++r){
    acc[r] += __shfl_xor(acc[r], 1);
    acc[r] += __shfl_xor(acc[r], 2);
    acc[r] += __shfl_xor(acc[r], 4);
    acc[r] += __shfl_xor(acc[r], 8);
    acc[r] += __shfl_xor(acc[r], 16);
    acc[r] += __shfl_xor(acc[r], 32);
  }
  if (jg == 0){
#pragma unroll
    for (int r = 0; r < RPB; ++r){
      float ud = aload(&V[d * N_TRAIN + rowbase + r]);
      wfin[r * 16 + d] = gd * (acc[r] - ud);   // subtract diagonal (sq=0 -> exp=1)
    }
  }
}

__global__ __launch_bounds__(NTHR, 1)
void gp_rollout_kernel(const float* __restrict__ xtr, const float* __restrict__ ytr,
                       const float* __restrict__ ls,  const float* __restrict__ var,
                       const float* __restrict__ noi, const float* __restrict__ st0,
                       const float* __restrict__ act, const float* __restrict__ eps,
                       float* __restrict__ out, float* __restrict__ ws)
{
  cg::grid_group grid = cg::this_grid();
  const int tid = threadIdx.x;
  const int bid = blockIdx.x;
  const int rowbase = bid * RPB;

  float* PV0  = ws + OFF_PV0;
  float* PV1  = ws + OFF_PV1;
  float* AA0  = ws + OFF_AA0;
  float* AA1  = ws + OFF_AA1;
  float* ALPH = ws + OFF_AL;
  float* RES  = ws + OFF_RES;
  float* RES2 = ws + OFF_RES2;
  unsigned int* syn = (unsigned int*)(ws + OFF_SYN);

  __shared__ __half sqh[RPB * SQS];            // 65.8 KB
  __shared__ float act_s[HORIZON * DACT];      // 2 KB
  __shared__ float eps_s[HORIZON * DOUT];      // 4 KB
  __shared__ float pr[768];
  __shared__ float wfin[256];
  __shared__ float dsum[48];
  __shared__ float xcur[32];
  __shared__ float xrows[RPB * DIN];           // 1.5 KB
  __shared__ float pv_s[256], v_s[256], yb_s[256];
  __shared__ float ce_s[16], g_s[16], s_s[16], var_s[16], nv_s[16];
  __shared__ float un_s[16], lam_s[16], sig_s[16], cb_s[16], ca_s[16];

  if (tid < 16){
    float l2 = ls[tid] * ls[tid];
    float nv = noi[tid] * noi[tid];
    float sd = var[tid] + nv + JITTER;
    ce_s[tid]  = -0.72134752044448f / l2;   // -0.5*log2(e)/ls^2
    g_s[tid]   = var[tid] / sd;
    s_s[tid]   = sd;
    var_s[tid] = var[tid];
    nv_s[tid]  = nv;
    un_s[tid]  = (float)N_TRAIN;            // ||ones||^2
  }
  if (tid < RPB * DIN) xrows[tid] = xtr[rowbase * DIN + tid];
  if (tid < HORIZON * DACT) act_s[tid] = act[tid];
  if (tid < HORIZON * DOUT) eps_s[tid] = eps[tid];
  __syncthreads();

  // -------- Phase 0: 16 sq rows -> LDS fp16; caches; zero RES/RES2/syn ------
  if (tid < 256){
    const int dd = tid >> 4, r = tid & 15;
    yb_s[tid] = ytr[(rowbase + r) * DOUT + dd] / s_s[dd];
    astore(&PV0[dd * N_TRAIN + rowbase + r], 1.0f);
    pv_s[tid] = 1.0f;
  }
  {
    const int r    = tid >> 6;      // 0..15, 64 threads per row
    const int lane = tid & 63;
    float xl[DIN];
#pragma unroll
    for (int k = 0; k < DIN; ++k) xl[k] = xrows[r * DIN + k];
    for (int q = 0; q < 32; ++q){
      const int j = lane + (q << 6);
      const float4* xp = reinterpret_cast<const float4*>(xtr + j * DIN);
      float sacc = 0.f;
#pragma unroll
      for (int v4 = 0; v4 < 6; ++v4){
        float4 x4 = xp[v4];
        float e0 = xl[v4*4+0] - x4.x, e1 = xl[v4*4+1] - x4.y;
        float e2 = xl[v4*4+2] - x4.z, e3 = xl[v4*4+3] - x4.w;
        sacc = fmaf(e0,e0, fmaf(e1,e1, fmaf(e2,e2, fmaf(e3,e3, sacc))));
      }
      sqh[r * SQS + j] = __float2half_rn(sacc);
    }
  }
  {
    int i = bid * NTHR + tid;
    if (i < MAXPC * 6144) RES[i] = 0.f;          // regular stores; grid.sync flushes
  }
  if (tid < 64) RES2[bid * 64 + tid] = 0.f;      // zero 64*64 (value,tag) pairs
  if (bid == 0 && tid < 512) syn[tid] = 0u;
  __syncthreads();
  __threadfence();
  grid.sync();            // single cooperative sync: init visibility everywhere
  int pc = 0;

  const int d  = tid >> 6;   // 0..15, one wave per output
  const int jg = tid & 63;
  const int lane8 = bid & 7;

  // -------- Power iteration (5) ----------------------------------------------
  float* PVc = PV0; float* PVn = PV1;
#pragma unroll 1
  for (int it = 0; it < POWER_ITERS; ++it){
    const bool last = (it == POWER_ITERS - 1);
    sweep(sqh, PVc, ce_s[d], g_s[d], wfin, rowbase, d, jg);
    __syncthreads();
    if (tid < 256){
      const int dd = tid >> 4, r = tid & 15, rowg = rowbase + r;
      float w = wfin[r * 16 + dd];
      astore(&PVn[dd * N_TRAIN + rowg], w);
      float u = pv_s[tid];
      pv_s[tid] = w;
      pr[tid]       = w * w;
      pr[256 + tid] = u * w;
      pr[512 + tid] = last ? yb_s[tid] * w : 0.f;
    }
    __syncthreads();
    ++pc;
    if (tid < 48){
      const int slot = tid >> 4, dd = tid & 15;
      float s = 0.f;
#pragma unroll
      for (int r = 0; r < 16; ++r) s += pr[slot * 256 + dd * 16 + r];
      atomicAdd(&RES[pc * 6144 + (tid * 8 + lane8) * 16], s);
    }
    gbar_pre(syn, pc, true);
    if (tid < 48){
      const float* base = &RES[pc * 6144 + tid * 128];
      float s = 0.f;
#pragma unroll
      for (int l = 0; l < 8; ++l) s += aload(base + l * 16);
      dsum[tid] = s;
    }
    __syncthreads();
    if (tid < 16){
      float ww = dsum[tid];        // slot0: w.w
      float uw = dsum[16 + tid];   // slot1: u.w
      if (last){
        lam_s[tid] = uw / fmaxf(un_s[tid], 1e-30f);   // Rayleigh quotient
        float sg = rsqrtf(fmaxf(ww, 1e-38f));
        sig_s[tid] = sg;
        cb_s[tid]  = sg * dsum[32 + tid];              // v1^T (y/s)
      }
      un_s[tid] = ww;
    }
    __syncthreads();
    float* tmp = PVc; PVc = PVn; PVn = tmp;
  }

  // -------- a0 = b - cb*v1 ; analytically v^T a0 = 0 -------------------------
  if (tid < 256){
    const int dd = tid >> 4, r = tid & 15, rowg = rowbase + r;
    float v = sig_s[dd] * pv_s[tid];
    v_s[tid] = v;
    astore(&AA0[dd * N_TRAIN + rowg], yb_s[tid] - cb_s[dd] * v);
  }
  if (tid < 16) ca_s[tid] = 0.f;                 // v unit => v^T a0 = cb - cb = 0
  ++pc;
  gbar_pre(syn, pc, true);                       // visibility of AA0

  // -------- Richardson (8) on deflated operator ------------------------------
  float* Ac = AA0; float* An = AA1;
#pragma unroll 1
  for (int it = 0; it < RICH_ITERS; ++it){
    const bool last = (it == RICH_ITERS - 1);
    sweep(sqh, Ac, ce_s[d], g_s[d], wfin, rowbase, d, jg);
    __syncthreads();
    if (tid < 256){
      const int dd = tid >> 4, r = tid & 15, rowg = rowbase + r;
      float w = wfin[r * 16 + dd];
      float v = v_s[tid];
      float bperp = yb_s[tid] - cb_s[dd] * v;
      float anew = bperp - (w - lam_s[dd] * ca_s[dd] * v);
      if (last){
        astore(&ALPH[dd * N_TRAIN + rowg], anew + (cb_s[dd] / (1.f + lam_s[dd])) * v);
      } else {
        astore(&An[dd * N_TRAIN + rowg], anew);
        pr[tid] = v * anew;
      }
    }
    __syncthreads();
    ++pc;
    if (last){
      gbar_pre(syn, pc, bid < NROLL);   // blocks >= NROLL: arrive-only, exit
      if (bid >= NROLL) return;
      break;
    }
    if (tid < 16){
      float s = 0.f;
#pragma unroll
      for (int r = 0; r < 16; ++r) s += pr[tid * 16 + r];
      atomicAdd(&RES[pc * 6144 + (tid * 8 + lane8) * 16], s);
    }
    gbar_pre(syn, pc, true);
    if (tid < 16){
      const float* base = &RES[pc * 6144 + tid * 128];
      float s = 0.f;
#pragma unroll
      for (int l = 0; l < 8; ++l) s += aload(base + l * 16);
      ca_s[tid] = s;
    }
    __syncthreads();
    float* tmp = Ac; Ac = An; An = tmp;
  }

  // ======== Rollout: NROLL blocks; tag-in-payload sync; LDS epilogue =========
  const int dd_own = bid;
  const float ced = ce_s[dd_own], vd = var_s[dd_own];

  // fp32 alpha/v for this thread's two training points (registers)
  const int p0 = 2 * tid, p1 = 2 * tid + 1;
  float a0r = aload(&ALPH[dd_own * N_TRAIN + p0]);
  float a1r = aload(&ALPH[dd_own * N_TRAIN + p1]);
  float v0r = sig_s[dd_own] * aload(&PVc[dd_own * N_TRAIN + p0]);
  float v1r = sig_s[dd_own] * aload(&PVc[dd_own * N_TRAIN + p1]);

  float xp0[DIN], xp1[DIN];
#pragma unroll
  for (int k = 0; k < DIN; ++k){
    xp0[k] = xtr[p0 * DIN + k];
    xp1[k] = xtr[p1 * DIN + k];
  }
  if (tid < 16) xcur[tid] = st0[tid];
  if (tid >= 16 && tid < 24) xcur[tid] = act_s[tid - 16];
  __syncthreads();

#pragma unroll 1
  for (int t = 0; t < HORIZON; ++t){
    // d2 + dots for this block's output (registers only)
    float sx = 0.f, sy = 0.f;
#pragma unroll
    for (int k = 0; k < DIN; ++k){
      float xc = xcur[k];
      float e0 = xc - xp0[k], e1 = xc - xp1[k];
      sx = fmaf(e0, e0, sx); sy = fmaf(e1, e1, sy);
    }
    float k0 = vd * fexp2(ced * sx);
    float k1 = vd * fexp2(ced * sy);
    float am = fmaf(k0, a0r, k1 * a1r);
    float ac = fmaf(k0, v0r, k1 * v1r);
    float ak = fmaf(k0, k0,  k1 * k1);
#pragma unroll
    for (int off = 1; off < 64; off <<= 1){
      am += __shfl_xor(am, off);
      ac += __shfl_xor(ac, off);
      ak += __shfl_xor(ak, off);
    }
    if ((tid & 63) == 0){
      const int wv = tid >> 6;
      pr[wv * 3 + 0] = am; pr[wv * 3 + 1] = ac; pr[wv * 3 + 2] = ak;
    }
    __syncthreads();
    // wave 0: publish tagged partials, poll all 48 (tight, 16 pollers only),
    // hand results to LDS — all 48 source lanes active at the dsum write.
    if (tid < 64){
      const unsigned int want = (unsigned int)(t + 1);
      if (tid < 3){
        float s = 0.f;
#pragma unroll
        for (int w = 0; w < 16; ++w) s += pr[w * 3 + tid];
        float2 pv; pv.x = s;
        pv.y = __uint_as_float(want);
        astore2(&RES2[(t * 64 + dd_own * 3 + tid) * 2], pv);
      }
      float val = 0.f;
      {
        const float* base = &RES2[t * 128];
        while (true){
          float2 pv = (tid < 48) ? aload2(base + 2 * tid)
                                 : make_float2(0.f, __uint_as_float(want));
          if (__all(__float_as_uint(pv.y) == want)){ val = pv.x; break; }
        }
      }
      if (tid < 48) dsum[tid] = val;
    }
    __syncthreads();
    if (tid < 16){
      const int dd = tid;
      float mean = dsum[3*dd], c = dsum[3*dd+1], kk = dsum[3*dd+2];
      float lam = lam_s[dd];
      float qs = c * c / (1.f + lam) + (kk - c * c);   // k^T Ky^-1 k * s
      float q  = qs / s_s[dd];
      float pvv = var_s[dd] - q + nv_s[dd];
      float sd = sqrtf(fmaxf(pvv, 1e-12f));
      float ns = mean + sd * eps_s[t * DOUT + dd];
      xcur[dd] = ns;                     // identical in every block
      float rs = ns, cs = ns * ns;
      rs += __shfl_down(rs, 8);  cs += __shfl_down(cs, 8);
      rs += __shfl_down(rs, 4);  cs += __shfl_down(cs, 4);
      rs += __shfl_down(rs, 2);  cs += __shfl_down(cs, 2);
      rs += __shfl_down(rs, 1);  cs += __shfl_down(cs, 1);
      if (bid == 0){
        out[t * DOUT + dd]        = ns;     // trajectory
        out[1152 + t * DOUT + dd] = mean;   // means
        out[2176 + t * DOUT + dd] = sd;     // stds
        if (dd == 0){ out[1024 + t] = rs; out[1088 + t] = cs; }  // reward, cost
      }
    } else if (tid >= 16 && tid < 24 && t + 1 < HORIZON){
      xcur[tid] = act_s[(t + 1) * DACT + (tid - 16)];
    }
    __syncthreads();
  }
}

extern "C" void kernel_launch(void* const* d_in, const int* in_sizes, int n_in,
                              void* d_out, int out_size, void* d_ws, size_t ws_size,
                              hipStream_t stream) {
  (void)in_sizes; (void)n_in; (void)out_size; (void)ws_size;
  const float* xtr = (const float*)d_in[0];
  const float* ytr = (const float*)d_in[1];
  const float* ls  = (const float*)d_in[2];
  const float* var = (const float*)d_in[3];
  const float* noi = (const float*)d_in[4];
  const float* st0 = (const float*)d_in[5];
  const float* act = (const float*)d_in[6];
  const float* eps = (const float*)d_in[7];
  float* out = (float*)d_out;
  float* ws  = (float*)d_ws;
  void* args[] = { &xtr, &ytr, &ls, &var, &noi, &st0, &act, &eps, &out, &ws };
  hipLaunchCooperativeKernel((const void*)gp_rollout_kernel,
                             dim3(NBLK), dim3(NTHR), args, 0, stream);
}